// Round 8
// baseline (122.404 us; speedup 1.0000x reference)
//
#include <hip/hip_runtime.h>
#include <math.h>

#define NN 4096
#define DD 128
#define ALPHA_C 16.0f
#define KSEL 32         // threshold = (K+1)-th smallest, 0-based index K

typedef __attribute__((ext_vector_type(8))) short bf16x8;
typedef __attribute__((ext_vector_type(4))) float f32x4;

// ---- float <-> order-preserving u32 key ----
__device__ __forceinline__ unsigned f2k(float f) {
  unsigned b = __float_as_uint(f);
  return (b & 0x80000000u) ? ~b : (b | 0x80000000u);
}
__device__ __forceinline__ float k2f(unsigned k) {
  unsigned b = (k & 0x80000000u) ? (k & 0x7FFFFFFFu) : ~k;
  return __uint_as_float(b);
}

// ---- wave (64-lane) butterfly reductions ----
__device__ __forceinline__ double wsum_d(double v) {
  #pragma unroll
  for (int m = 32; m; m >>= 1) v += __shfl_xor(v, m, 64);
  return v;
}
__device__ __forceinline__ int wsum_i(int v) {
  #pragma unroll
  for (int m = 32; m; m >>= 1) v += __shfl_xor(v, m, 64);
  return v;
}
__device__ __forceinline__ float wmin_f(float v) {
  #pragma unroll
  for (int m = 32; m; m >>= 1) v = fminf(v, __shfl_xor(v, m, 64));
  return v;
}

// ---- kernel 1: split x (f32) -> bf16 hi + bf16 lo (RNE both) ----
__global__ __launch_bounds__(256) void nca_prep(
    const float* __restrict__ x, short* __restrict__ xhi, short* __restrict__ xlo) {
  int idx = blockIdx.x * blockDim.x + threadIdx.x;   // 0 .. N*D/4-1
  float4 v = reinterpret_cast<const float4*>(x)[idx];
  float vv[4] = {v.x, v.y, v.z, v.w};
  short h[4], l[4];
  #pragma unroll
  for (int q = 0; q < 4; ++q) {
    unsigned u  = __float_as_uint(vv[q]);
    unsigned hb = (u + 0x7FFFu + ((u >> 16) & 1u)) >> 16;
    float hf    = __uint_as_float(hb << 16);
    float lf    = vv[q] - hf;
    unsigned ul = __float_as_uint(lf);
    unsigned lb = (ul + 0x7FFFu + ((ul >> 16) & 1u)) >> 16;
    h[q] = (short)hb; l[q] = (short)lb;
  }
  reinterpret_cast<short4*>(xhi)[idx] = make_short4(h[0], h[1], h[2], h[3]);
  reinterpret_cast<short4*>(xlo)[idx] = make_short4(l[0], l[1], l[2], l[3]);
}

// ---- kernel 2: MFMA GEMM sim = X X^T (bf16x3) -> u32 keys ----
// block: 32 rows x 256 cols, 4 waves; wave: 32 rows x 64 cols = 2x4 16x16 tiles
__global__ __launch_bounds__(256) void nca_gemm(
    const short* __restrict__ xhi, const short* __restrict__ xlo,
    unsigned* __restrict__ keys) {
  const int tid = threadIdx.x;
  const int w   = tid >> 6;
  const int l   = tid & 63;
  const int rg  = blockIdx.x >> 4;
  const int cg  = blockIdx.x & 15;
  const int R   = rg << 5;                 // 32 rows
  const int C   = (cg << 8) + (w << 6);    // 64 cols per wave
  const int lr  = l & 15;                  // row/col within tile
  const int lk  = (l >> 4) << 3;           // k-offset within 32-wide k-block

  f32x4 acc[2][4];
  #pragma unroll
  for (int rt = 0; rt < 2; ++rt)
    #pragma unroll
    for (int t = 0; t < 4; ++t) acc[rt][t] = (f32x4){0.f, 0.f, 0.f, 0.f};

  #pragma unroll
  for (int kb = 0; kb < 4; ++kb) {
    const int ko = (kb << 5) + lk;
    bf16x8 ah[2], al[2], bh[4], bl[4];
    #pragma unroll
    for (int rt = 0; rt < 2; ++rt) {
      const size_t off = (size_t)(R + (rt << 4) + lr) * DD + ko;
      ah[rt] = *reinterpret_cast<const bf16x8*>(xhi + off);
      al[rt] = *reinterpret_cast<const bf16x8*>(xlo + off);
    }
    #pragma unroll
    for (int t = 0; t < 4; ++t) {
      const size_t off = (size_t)(C + (t << 4) + lr) * DD + ko;
      bh[t] = *reinterpret_cast<const bf16x8*>(xhi + off);
      bl[t] = *reinterpret_cast<const bf16x8*>(xlo + off);
    }
    #pragma unroll
    for (int rt = 0; rt < 2; ++rt)
      #pragma unroll
      for (int t = 0; t < 4; ++t) {
        acc[rt][t] = __builtin_amdgcn_mfma_f32_16x16x32_bf16(ah[rt], bh[t], acc[rt][t], 0, 0, 0);
        acc[rt][t] = __builtin_amdgcn_mfma_f32_16x16x32_bf16(ah[rt], bl[t], acc[rt][t], 0, 0, 0);
        acc[rt][t] = __builtin_amdgcn_mfma_f32_16x16x32_bf16(al[rt], bh[t], acc[rt][t], 0, 0, 0);
      }
  }

  // C/D layout (m89-verified): col = lane&15, row = (lane>>4)*4 + reg
  const int rbase = (l >> 4) << 2;
  const int cc    = l & 15;
  #pragma unroll
  for (int rt = 0; rt < 2; ++rt)
    #pragma unroll
    for (int t = 0; t < 4; ++t)
      #pragma unroll
      for (int r = 0; r < 4; ++r)
        keys[(size_t)(R + (rt << 4) + rbase + r) * NN + C + (t << 4) + cc] =
            f2k(acc[rt][t][r]);
}

// ---- kernel 3: per-row select + sums. 1 wave = 1 row, 4 waves/block ----
// Keys live in LDS (16 KB/row): architecturally spill-proof. Rounds 5-7
// showed the compiler refuses >84 VGPRs here and spills kv[64] to scratch
// regardless of launch_bounds; LDS residence removes the heuristic entirely.
__global__ __launch_bounds__(256) void nca_select(
    const float* __restrict__ x, const unsigned* __restrict__ keys,
    const int* __restrict__ tgt, float* __restrict__ row_loss,
    float* __restrict__ out) {
  __shared__ unsigned klds[4][NN];     // 64 KB: one key-row per wave
  __shared__ unsigned cbuf[4][64];     // 1 KB: candidate compaction

  const int tid  = threadIdx.x;
  const int w    = tid >> 6;
  const int lane = tid & 63;
  const int i    = blockIdx.x * 4 + w;
  const int ti   = tgt[i];
  const int lb   = lane << 2;
  const unsigned* krow = keys + (size_t)i * NN;

  // f64 self-dot (decision sim[i][i] < 1.0 must match f64-accurate reference)
  double sx0 = (double)x[i * DD + lane], sx1 = (double)x[i * DD + lane + 64];
  const double selfd = wsum_d(sx0 * sx0 + sx1 * sx1);
  const bool self_pos = (selfd < 1.0);

  // stream keys -> LDS; base = row mean of decoded sims (f64, pre-exclusion)
  double bs = 0.0;
  #pragma unroll
  for (int kk = 0; kk < 16; ++kk) {
    uint4 k4 = *reinterpret_cast<const uint4*>(krow + (kk << 8) + lb);
    bs += (double)k2f(k4.x) + (double)k2f(k4.y) +
          (double)k2f(k4.z) + (double)k2f(k4.w);
    *reinterpret_cast<uint4*>(&klds[w][(kk << 8) + lb]) = k4;
  }
  const float basef = (float)(wsum_d(bs) * (1.0 / NN));

  // exclude self (sim>=1): max key (decodes to NaN in pass 2).
  // Same-wave ds_write -> ds_read ordering is guaranteed via lgkmcnt.
  if (!self_pos && lane == 0) klds[w][i] = 0xFFFFFFFFu;

  // ---- exact rank-KSEL: bitwise binary search until window <= 64 ----
  // Invariant: target key in [lo, lo+2^(b+1)); nLo=count(<lo), nHi=count(<hi).
  unsigned lo = 0;
  int nLo = 0, nHi = NN, b = 31;
  while (b >= 0 && (nHi - nLo) > 64) {
    unsigned mid = lo | (1u << b);
    int c = 0;
    #pragma unroll
    for (int kk = 0; kk < 16; ++kk) {
      uint4 v = *reinterpret_cast<const uint4*>(&klds[w][(kk << 8) + lb]);
      c += (int)__popcll(__ballot(v.x < mid));
      c += (int)__popcll(__ballot(v.y < mid));
      c += (int)__popcll(__ballot(v.z < mid));
      c += (int)__popcll(__ballot(v.w < mid));
    }
    if (c <= KSEL) { lo = mid; nLo = c; }
    else nHi = c;
    --b;
  }

  unsigned keysel;
  if ((nHi - nLo) <= 64) {
    // compact window candidates (prefix == lo >> shift) one-per-lane.
    // Window bucket [lo, lo+2^shift) holds exactly nHi-nLo <= 64 keys.
    const int shift = b + 1;                   // <= 31 (loop ran >= once)
    const unsigned pfx = lo >> shift;
    int cnt = 0;
    #pragma unroll
    for (int kk = 0; kk < 16; ++kk) {
      uint4 v = *reinterpret_cast<const uint4*>(&klds[w][(kk << 8) + lb]);
      cnt += ((v.x >> shift) == pfx) + ((v.y >> shift) == pfx) +
             ((v.z >> shift) == pfx) + ((v.w >> shift) == pfx);
    }
    int incl = cnt;
    #pragma unroll
    for (int off = 1; off < 64; off <<= 1) {
      int o = __shfl_up(incl, off, 64);
      if (lane >= off) incl += o;
    }
    const int total = __shfl(incl, 63, 64);
    int idx = incl - cnt;
    #pragma unroll
    for (int kk = 0; kk < 16; ++kk) {
      uint4 v4 = *reinterpret_cast<const uint4*>(&klds[w][(kk << 8) + lb]);
      unsigned vv[4] = {v4.x, v4.y, v4.z, v4.w};
      #pragma unroll
      for (int q = 0; q < 4; ++q)
        if ((vv[q] >> shift) == pfx) cbuf[w][idx++] = vv[q];
    }
    unsigned v = cbuf[w][lane];                // garbage if lane >= total (masked)

    unsigned long long amask =
        (total >= 64) ? ~0ull : ((1ull << total) - 1ull);
    int ww = KSEL - nLo;                       // 0-based rank within window
    for (int bb = b; bb >= 0; --bb) {
      unsigned long long z = __ballot(((amask >> lane) & 1ull) &&
                                      (((v >> bb) & 1u) == 0u));
      int zc = __popcll(z);
      if (ww < zc) amask = z;
      else { ww -= zc; amask &= ~z; }
    }
    int first = __ffsll((unsigned long long)amask) - 1;
    keysel = __shfl(v, first, 64);
  } else {
    keysel = lo;  // bits exhausted with >64 exact ties: key fully resolved
  }
  const float thr = k2f(keysel);

  // ---- pass 2: weighted sums below threshold, min positive, has-pos ----
  double psum = 0.0, nsum = 0.0;
  float minp = __builtin_inff();
  int hasp = 0;
  #pragma unroll
  for (int kk = 0; kk < 16; ++kk) {
    uint4 v4 = *reinterpret_cast<const uint4*>(&klds[w][(kk << 8) + lb]);
    int4  t4 = *reinterpret_cast<const int4*>(tgt + (kk << 8) + lb);
    unsigned vv[4] = {v4.x, v4.y, v4.z, v4.w};
    int tj[4] = {t4.x, t4.y, t4.z, t4.w};
    #pragma unroll
    for (int q = 0; q < 4; ++q) {
      int j = (kk << 8) + lb + q;
      float s = k2f(vv[q]);    // NaN for excluded self -> all predicates false
      bool same = (tj[q] == ti);
      bool vpos = same && ((j == i) ? self_pos : (s < 1.0f));
      if (vpos) minp = fminf(minp, s);
      if (s < thr) {
        float wgt = expf(ALPHA_C * (basef - s));
        if (vpos) { psum += (double)wgt; hasp = 1; }
        else if (!same) nsum += (double)wgt;
      }
    }
  }
  double tpsum = wsum_d(psum);
  double tnsum = wsum_d(nsum);
  float  tminp = wmin_f(minp);
  int    thasp = wsum_i(hasp);

  // diagnostics from the last row only (wave-uniform branch)
  if (i == NN - 1) {
    double pss = 0.0, nss = 0.0;
    int pct = 0, nct = 0;
    #pragma unroll
    for (int kk = 0; kk < 16; ++kk) {
      uint4 v4 = *reinterpret_cast<const uint4*>(&klds[w][(kk << 8) + lb]);
      int4  t4 = *reinterpret_cast<const int4*>(tgt + (kk << 8) + lb);
      unsigned vv[4] = {v4.x, v4.y, v4.z, v4.w};
      int tj[4] = {t4.x, t4.y, t4.z, t4.w};
      #pragma unroll
      for (int q = 0; q < 4; ++q) {
        int j = (kk << 8) + lb + q;
        float s = k2f(vv[q]);
        bool same = (tj[q] == ti);
        bool vpos = same && ((j == i) ? self_pos : (s < 1.0f));
        if (vpos) { pss += (double)s; pct++; }
        if (!same) { nss += (double)s; nct++; }
      }
    }
    pss = wsum_d(pss); nss = wsum_d(nss);
    pct = wsum_i(pct); nct = wsum_i(nct);
    if (lane == 0) {
      out[2] = (float)(pss / (double)pct);
      out[3] = (float)(nss / (double)nct);
    }
  }

  if (lane == 0) {
    float pl = (thasp > 0) ? (float)tpsum
                           : expf(ALPHA_C * (basef - tminp));
    row_loss[i] = -logf(pl / (pl + (float)tnsum));
  }
}

// ---- kernel 4: deterministic mean of per-row losses ----
__global__ void nca_final(const float* __restrict__ row_loss, float* __restrict__ out) {
  __shared__ double redd[4];
  int tid = threadIdx.x;
  double s = 0.0;
  for (int i = tid; i < NN; i += 256) s += (double)row_loss[i];
  #pragma unroll
  for (int m = 32; m; m >>= 1) s += __shfl_xor(s, m, 64);
  if ((tid & 63) == 0) redd[tid >> 6] = s;
  __syncthreads();
  if (tid == 0) {
    double tot = redd[0] + redd[1] + redd[2] + redd[3];
    out[0] = (float)(tot * (1.0 / NN));
    out[1] = 0.0f;
  }
}

extern "C" void kernel_launch(void* const* d_in, const int* in_sizes, int n_in,
                              void* d_out, int out_size, void* d_ws, size_t ws_size,
                              hipStream_t stream) {
  const float* x  = (const float*)d_in[0];
  const int* tgt  = (const int*)d_in[1];
  float* out      = (float*)d_out;

  // ws layout: xhi (1 MB) | xlo (1 MB) | row_loss (16 KB) | keys (64 MB)
  short* xhi       = (short*)d_ws;
  short* xlo       = xhi + (size_t)NN * DD;
  float* row_loss  = (float*)(xlo + (size_t)NN * DD);
  unsigned* keys   = (unsigned*)(row_loss + NN);

  nca_prep<<<(NN * DD / 4) / 256, 256, 0, stream>>>(x, xhi, xlo);
  nca_gemm<<<(NN / 32) * (NN / 256), 256, 0, stream>>>(xhi, xlo, keys);
  nca_select<<<NN / 4, 256, 0, stream>>>(x, keys, tgt, row_loss, out);
  nca_final<<<1, 256, 0, stream>>>(row_loss, out);
}

// Round 9
// 120.593 us; speedup vs baseline: 1.0150x; 1.0150x over previous
//
#include <hip/hip_runtime.h>
#include <math.h>

#define NN 4096
#define DD 128
#define ALPHA_C 16.0f
#define KSEL 32         // threshold = (K+1)-th smallest, 0-based index K

typedef __attribute__((ext_vector_type(8))) short bf16x8;
typedef __attribute__((ext_vector_type(4))) float f32x4;

// ---- float <-> order-preserving u32 key ----
__device__ __forceinline__ unsigned f2k(float f) {
  unsigned b = __float_as_uint(f);
  return (b & 0x80000000u) ? ~b : (b | 0x80000000u);
}
__device__ __forceinline__ float k2f(unsigned k) {
  unsigned b = (k & 0x80000000u) ? (k & 0x7FFFFFFFu) : ~k;
  return __uint_as_float(b);
}

// ---- wave (64-lane) butterfly reductions ----
__device__ __forceinline__ double wsum_d(double v) {
  #pragma unroll
  for (int m = 32; m; m >>= 1) v += __shfl_xor(v, m, 64);
  return v;
}
__device__ __forceinline__ int wsum_i(int v) {
  #pragma unroll
  for (int m = 32; m; m >>= 1) v += __shfl_xor(v, m, 64);
  return v;
}
__device__ __forceinline__ float wmin_f(float v) {
  #pragma unroll
  for (int m = 32; m; m >>= 1) v = fminf(v, __shfl_xor(v, m, 64));
  return v;
}

// ---- kernel 1: split x (f32) -> bf16 hi + bf16 lo (RNE both) ----
__global__ __launch_bounds__(256) void nca_prep(
    const float* __restrict__ x, short* __restrict__ xhi, short* __restrict__ xlo) {
  int idx = blockIdx.x * blockDim.x + threadIdx.x;   // 0 .. N*D/4-1
  float4 v = reinterpret_cast<const float4*>(x)[idx];
  float vv[4] = {v.x, v.y, v.z, v.w};
  short h[4], l[4];
  #pragma unroll
  for (int q = 0; q < 4; ++q) {
    unsigned u  = __float_as_uint(vv[q]);
    unsigned hb = (u + 0x7FFFu + ((u >> 16) & 1u)) >> 16;
    float hf    = __uint_as_float(hb << 16);
    float lf    = vv[q] - hf;
    unsigned ul = __float_as_uint(lf);
    unsigned lb = (ul + 0x7FFFu + ((ul >> 16) & 1u)) >> 16;
    h[q] = (short)hb; l[q] = (short)lb;
  }
  reinterpret_cast<short4*>(xhi)[idx] = make_short4(h[0], h[1], h[2], h[3]);
  reinterpret_cast<short4*>(xlo)[idx] = make_short4(l[0], l[1], l[2], l[3]);
}

// ---- kernel 2: MFMA GEMM sim = X X^T (bf16x3) -> u32 keys ----
// block: 32 rows x 256 cols, 4 waves; wave: 32 rows x 64 cols = 2x4 16x16 tiles
__global__ __launch_bounds__(256) void nca_gemm(
    const short* __restrict__ xhi, const short* __restrict__ xlo,
    unsigned* __restrict__ keys) {
  const int tid = threadIdx.x;
  const int w   = tid >> 6;
  const int l   = tid & 63;
  const int rg  = blockIdx.x >> 4;
  const int cg  = blockIdx.x & 15;
  const int R   = rg << 5;                 // 32 rows
  const int C   = (cg << 8) + (w << 6);    // 64 cols per wave
  const int lr  = l & 15;                  // row/col within tile
  const int lk  = (l >> 4) << 3;           // k-offset within 32-wide k-block

  f32x4 acc[2][4];
  #pragma unroll
  for (int rt = 0; rt < 2; ++rt)
    #pragma unroll
    for (int t = 0; t < 4; ++t) acc[rt][t] = (f32x4){0.f, 0.f, 0.f, 0.f};

  #pragma unroll
  for (int kb = 0; kb < 4; ++kb) {
    const int ko = (kb << 5) + lk;
    bf16x8 ah[2], al[2], bh[4], bl[4];
    #pragma unroll
    for (int rt = 0; rt < 2; ++rt) {
      const size_t off = (size_t)(R + (rt << 4) + lr) * DD + ko;
      ah[rt] = *reinterpret_cast<const bf16x8*>(xhi + off);
      al[rt] = *reinterpret_cast<const bf16x8*>(xlo + off);
    }
    #pragma unroll
    for (int t = 0; t < 4; ++t) {
      const size_t off = (size_t)(C + (t << 4) + lr) * DD + ko;
      bh[t] = *reinterpret_cast<const bf16x8*>(xhi + off);
      bl[t] = *reinterpret_cast<const bf16x8*>(xlo + off);
    }
    #pragma unroll
    for (int rt = 0; rt < 2; ++rt)
      #pragma unroll
      for (int t = 0; t < 4; ++t) {
        acc[rt][t] = __builtin_amdgcn_mfma_f32_16x16x32_bf16(ah[rt], bh[t], acc[rt][t], 0, 0, 0);
        acc[rt][t] = __builtin_amdgcn_mfma_f32_16x16x32_bf16(ah[rt], bl[t], acc[rt][t], 0, 0, 0);
        acc[rt][t] = __builtin_amdgcn_mfma_f32_16x16x32_bf16(al[rt], bh[t], acc[rt][t], 0, 0, 0);
      }
  }

  // C/D layout (m89-verified): col = lane&15, row = (lane>>4)*4 + reg
  const int rbase = (l >> 4) << 2;
  const int cc    = l & 15;
  #pragma unroll
  for (int rt = 0; rt < 2; ++rt)
    #pragma unroll
    for (int t = 0; t < 4; ++t)
      #pragma unroll
      for (int r = 0; r < 4; ++r)
        keys[(size_t)(R + (rt << 4) + rbase + r) * NN + C + (t << 4) + cc] =
            f2k(acc[rt][t][r]);
}

// ---- kernel 3: per-row select + sums. 1 wave = 1 row, 4 waves/block ----
// Exact rank-KSEL via per-wave radix-256 select (4 levels): 4 full-row LDS
// scans total, vs 17-32 for the bitwise binary search (rounds 6-8 showed the
// scan count, not the storage medium, is the cost: ~100us all three rounds).
// Level-0 histogram is fused into staging. No barriers; hist is per-wave.
__global__ __launch_bounds__(256) void nca_select(
    const float* __restrict__ x, const unsigned* __restrict__ keys,
    const int* __restrict__ tgt, float* __restrict__ row_loss,
    float* __restrict__ out) {
  __shared__ unsigned klds[4][NN];     // 64 KB: one key-row per wave
  __shared__ int      hist[4][256];    // 4 KB: per-wave radix histogram

  const int tid  = threadIdx.x;
  const int w    = tid >> 6;
  const int lane = tid & 63;
  const int i    = blockIdx.x * 4 + w;
  const int ti   = tgt[i];
  const int lb   = lane << 2;
  const unsigned* krow = keys + (size_t)i * NN;

  // f64 self-dot (decision sim[i][i] < 1.0 must match f64-accurate reference)
  double sx0 = (double)x[i * DD + lane], sx1 = (double)x[i * DD + lane + 64];
  const double selfd = wsum_d(sx0 * sx0 + sx1 * sx1);
  const bool self_pos = (selfd < 1.0);

  // zero hist (same-wave DS ordering: zeros land before the atomics below)
  *reinterpret_cast<int4*>(&hist[w][lane << 2]) = make_int4(0, 0, 0, 0);

  // staging: keys -> LDS, base sum (raw values), level-0 histogram (top byte).
  // Excluded self (sim>=1) is substituted with max key BEFORE hist/write.
  double bs = 0.0;
  #pragma unroll
  for (int kk = 0; kk < 16; ++kk) {
    uint4 k4 = *reinterpret_cast<const uint4*>(krow + (kk << 8) + lb);
    bs += (double)k2f(k4.x) + (double)k2f(k4.y) +
          (double)k2f(k4.z) + (double)k2f(k4.w);
    unsigned vv[4] = {k4.x, k4.y, k4.z, k4.w};
    if (!self_pos) {
      #pragma unroll
      for (int q = 0; q < 4; ++q)
        if (((kk << 8) + lb + q) == i) vv[q] = 0xFFFFFFFFu;
    }
    #pragma unroll
    for (int q = 0; q < 4; ++q)
      atomicAdd(&hist[w][vv[q] >> 24], 1);
    *reinterpret_cast<uint4*>(&klds[w][(kk << 8) + lb]) =
        make_uint4(vv[0], vv[1], vv[2], vv[3]);
  }
  const float basef = (float)(wsum_d(bs) * (1.0 / NN));

  // ---- radix-256 select, 4 levels (level 0 hist already built) ----
  unsigned pref = 0;
  int want = KSEL;
  #pragma unroll
  for (int lvl = 0; lvl < 4; ++lvl) {
    if (lvl > 0) {
      *reinterpret_cast<int4*>(&hist[w][lane << 2]) = make_int4(0, 0, 0, 0);
      const int shp = 32 - 8 * lvl;        // prefix shift
      const int shd = 24 - 8 * lvl;        // digit shift
      #pragma unroll
      for (int kk = 0; kk < 16; ++kk) {
        uint4 v4 = *reinterpret_cast<const uint4*>(&klds[w][(kk << 8) + lb]);
        unsigned vv[4] = {v4.x, v4.y, v4.z, v4.w};
        #pragma unroll
        for (int q = 0; q < 4; ++q)
          if ((vv[q] >> shp) == pref)
            atomicAdd(&hist[w][(vv[q] >> shd) & 0xFFu], 1);
      }
    }
    int4 c4 = *reinterpret_cast<const int4*>(&hist[w][lane << 2]);
    int tot = c4.x + c4.y + c4.z + c4.w;
    int incl = tot;
    #pragma unroll
    for (int off = 1; off < 64; off <<= 1) {
      int o = __shfl_up(incl, off, 64);
      if (lane >= off) incl += o;
    }
    int excl = incl - tot;
    bool here = (want >= excl) && (want < incl);
    unsigned long long bal = __ballot(here);
    int L = __ffsll((unsigned long long)bal) - 1;
    int binl = 0, wl = want - excl;          // meaningful on lane L only
    if (wl >= c4.x) { wl -= c4.x; binl = 1;
      if (wl >= c4.y) { wl -= c4.y; binl = 2;
        if (wl >= c4.z) { wl -= c4.z; binl = 3; } } }
    int binsel = __shfl((lane << 2) + binl, L, 64);
    want = __shfl(wl, L, 64);
    pref = (pref << 8) | (unsigned)binsel;
  }
  const float thr = k2f(pref);

  // ---- pass 2: weighted sums below threshold, min positive, has-pos ----
  double psum = 0.0, nsum = 0.0;
  float minp = __builtin_inff();
  int hasp = 0;
  #pragma unroll
  for (int kk = 0; kk < 16; ++kk) {
    uint4 v4 = *reinterpret_cast<const uint4*>(&klds[w][(kk << 8) + lb]);
    int4  t4 = *reinterpret_cast<const int4*>(tgt + (kk << 8) + lb);
    unsigned vv[4] = {v4.x, v4.y, v4.z, v4.w};
    int tj[4] = {t4.x, t4.y, t4.z, t4.w};
    #pragma unroll
    for (int q = 0; q < 4; ++q) {
      int j = (kk << 8) + lb + q;
      float s = k2f(vv[q]);    // NaN for excluded self -> all predicates false
      bool same = (tj[q] == ti);
      bool vpos = same && ((j == i) ? self_pos : (s < 1.0f));
      if (vpos) minp = fminf(minp, s);
      if (s < thr) {
        float wgt = expf(ALPHA_C * (basef - s));
        if (vpos) { psum += (double)wgt; hasp = 1; }
        else if (!same) nsum += (double)wgt;
      }
    }
  }
  double tpsum = wsum_d(psum);
  double tnsum = wsum_d(nsum);
  float  tminp = wmin_f(minp);
  int    thasp = wsum_i(hasp);

  // diagnostics from the last row only (wave-uniform branch)
  if (i == NN - 1) {
    double pss = 0.0, nss = 0.0;
    int pct = 0, nct = 0;
    #pragma unroll
    for (int kk = 0; kk < 16; ++kk) {
      uint4 v4 = *reinterpret_cast<const uint4*>(&klds[w][(kk << 8) + lb]);
      int4  t4 = *reinterpret_cast<const int4*>(tgt + (kk << 8) + lb);
      unsigned vv[4] = {v4.x, v4.y, v4.z, v4.w};
      int tj[4] = {t4.x, t4.y, t4.z, t4.w};
      #pragma unroll
      for (int q = 0; q < 4; ++q) {
        int j = (kk << 8) + lb + q;
        float s = k2f(vv[q]);
        bool same = (tj[q] == ti);
        bool vpos = same && ((j == i) ? self_pos : (s < 1.0f));
        if (vpos) { pss += (double)s; pct++; }
        if (!same) { nss += (double)s; nct++; }
      }
    }
    pss = wsum_d(pss); nss = wsum_d(nss);
    pct = wsum_i(pct); nct = wsum_i(nct);
    if (lane == 0) {
      out[2] = (float)(pss / (double)pct);
      out[3] = (float)(nss / (double)nct);
    }
  }

  if (lane == 0) {
    float pl = (thasp > 0) ? (float)tpsum
                           : expf(ALPHA_C * (basef - tminp));
    row_loss[i] = -logf(pl / (pl + (float)tnsum));
  }
}

// ---- kernel 4: deterministic mean of per-row losses ----
__global__ void nca_final(const float* __restrict__ row_loss, float* __restrict__ out) {
  __shared__ double redd[4];
  int tid = threadIdx.x;
  double s = 0.0;
  for (int i = tid; i < NN; i += 256) s += (double)row_loss[i];
  #pragma unroll
  for (int m = 32; m; m >>= 1) s += __shfl_xor(s, m, 64);
  if ((tid & 63) == 0) redd[tid >> 6] = s;
  __syncthreads();
  if (tid == 0) {
    double tot = redd[0] + redd[1] + redd[2] + redd[3];
    out[0] = (float)(tot * (1.0 / NN));
    out[1] = 0.0f;
  }
}

extern "C" void kernel_launch(void* const* d_in, const int* in_sizes, int n_in,
                              void* d_out, int out_size, void* d_ws, size_t ws_size,
                              hipStream_t stream) {
  const float* x  = (const float*)d_in[0];
  const int* tgt  = (const int*)d_in[1];
  float* out      = (float*)d_out;

  // ws layout: xhi (1 MB) | xlo (1 MB) | row_loss (16 KB) | keys (64 MB)
  short* xhi       = (short*)d_ws;
  short* xlo       = xhi + (size_t)NN * DD;
  float* row_loss  = (float*)(xlo + (size_t)NN * DD);
  unsigned* keys   = (unsigned*)(row_loss + NN);

  nca_prep<<<(NN * DD / 4) / 256, 256, 0, stream>>>(x, xhi, xlo);
  nca_gemm<<<(NN / 32) * (NN / 256), 256, 0, stream>>>(xhi, xlo, keys);
  nca_select<<<NN / 4, 256, 0, stream>>>(x, keys, tgt, row_loss, out);
  nca_final<<<1, 256, 0, stream>>>(row_loss, out);
}

// Round 10
// 109.883 us; speedup vs baseline: 1.1140x; 1.0975x over previous
//
#include <hip/hip_runtime.h>
#include <math.h>

#define NN 4096
#define DD 128
#define ALPHA_C 16.0f
#define KSEL 32         // threshold = (K+1)-th smallest, 0-based index K

typedef __attribute__((ext_vector_type(8))) short bf16x8;
typedef __attribute__((ext_vector_type(4))) float f32x4;
typedef __attribute__((ext_vector_type(4))) unsigned uint4v;

// ---- float <-> order-preserving u32 key ----
__device__ __forceinline__ unsigned f2k(float f) {
  unsigned b = __float_as_uint(f);
  return (b & 0x80000000u) ? ~b : (b | 0x80000000u);
}
__device__ __forceinline__ float k2f(unsigned k) {
  unsigned b = (k & 0x80000000u) ? (k & 0x7FFFFFFFu) : ~k;
  return __uint_as_float(b);
}

// ---- wave (64-lane) butterfly reductions ----
__device__ __forceinline__ double wsum_d(double v) {
  #pragma unroll
  for (int m = 32; m; m >>= 1) v += __shfl_xor(v, m, 64);
  return v;
}
__device__ __forceinline__ int wsum_i(int v) {
  #pragma unroll
  for (int m = 32; m; m >>= 1) v += __shfl_xor(v, m, 64);
  return v;
}
__device__ __forceinline__ float wmin_f(float v) {
  #pragma unroll
  for (int m = 32; m; m >>= 1) v = fminf(v, __shfl_xor(v, m, 64));
  return v;
}

// ---- kernel 1: split x (f32) -> bf16 hi + bf16 lo (RNE both) ----
__global__ __launch_bounds__(256) void nca_prep(
    const float* __restrict__ x, short* __restrict__ xhi, short* __restrict__ xlo) {
  int idx = blockIdx.x * blockDim.x + threadIdx.x;   // 0 .. N*D/4-1
  float4 v = reinterpret_cast<const float4*>(x)[idx];
  float vv[4] = {v.x, v.y, v.z, v.w};
  short h[4], l[4];
  #pragma unroll
  for (int q = 0; q < 4; ++q) {
    unsigned u  = __float_as_uint(vv[q]);
    unsigned hb = (u + 0x7FFFu + ((u >> 16) & 1u)) >> 16;
    float hf    = __uint_as_float(hb << 16);
    float lf    = vv[q] - hf;
    unsigned ul = __float_as_uint(lf);
    unsigned lb = (ul + 0x7FFFu + ((ul >> 16) & 1u)) >> 16;
    h[q] = (short)hb; l[q] = (short)lb;
  }
  reinterpret_cast<short4*>(xhi)[idx] = make_short4(h[0], h[1], h[2], h[3]);
  reinterpret_cast<short4*>(xlo)[idx] = make_short4(l[0], l[1], l[2], l[3]);
}

// ---- kernel 2: MFMA GEMM sim = X X^T (bf16x3) -> u32 keys (NT stores) ----
// block: 32 rows x 256 cols, 4 waves; wave: 32 rows x 64 cols = 2x4 16x16 tiles
__global__ __launch_bounds__(256) void nca_gemm(
    const short* __restrict__ xhi, const short* __restrict__ xlo,
    unsigned* __restrict__ keys) {
  const int tid = threadIdx.x;
  const int w   = tid >> 6;
  const int l   = tid & 63;
  const int rg  = blockIdx.x >> 4;
  const int cg  = blockIdx.x & 15;
  const int R   = rg << 5;                 // 32 rows
  const int C   = (cg << 8) + (w << 6);    // 64 cols per wave
  const int lr  = l & 15;                  // row/col within tile
  const int lk  = (l >> 4) << 3;           // k-offset within 32-wide k-block

  f32x4 acc[2][4];
  #pragma unroll
  for (int rt = 0; rt < 2; ++rt)
    #pragma unroll
    for (int t = 0; t < 4; ++t) acc[rt][t] = (f32x4){0.f, 0.f, 0.f, 0.f};

  #pragma unroll
  for (int kb = 0; kb < 4; ++kb) {
    const int ko = (kb << 5) + lk;
    bf16x8 ah[2], al[2], bh[4], bl[4];
    #pragma unroll
    for (int rt = 0; rt < 2; ++rt) {
      const size_t off = (size_t)(R + (rt << 4) + lr) * DD + ko;
      ah[rt] = *reinterpret_cast<const bf16x8*>(xhi + off);
      al[rt] = *reinterpret_cast<const bf16x8*>(xlo + off);
    }
    #pragma unroll
    for (int t = 0; t < 4; ++t) {
      const size_t off = (size_t)(C + (t << 4) + lr) * DD + ko;
      bh[t] = *reinterpret_cast<const bf16x8*>(xhi + off);
      bl[t] = *reinterpret_cast<const bf16x8*>(xlo + off);
    }
    #pragma unroll
    for (int rt = 0; rt < 2; ++rt)
      #pragma unroll
      for (int t = 0; t < 4; ++t) {
        acc[rt][t] = __builtin_amdgcn_mfma_f32_16x16x32_bf16(ah[rt], bh[t], acc[rt][t], 0, 0, 0);
        acc[rt][t] = __builtin_amdgcn_mfma_f32_16x16x32_bf16(ah[rt], bl[t], acc[rt][t], 0, 0, 0);
        acc[rt][t] = __builtin_amdgcn_mfma_f32_16x16x32_bf16(al[rt], bh[t], acc[rt][t], 0, 0, 0);
      }
  }

  // C/D layout (m89-verified): col = lane&15, row = (lane>>4)*4 + reg
  const int rbase = (l >> 4) << 2;
  const int cc    = l & 15;
  #pragma unroll
  for (int rt = 0; rt < 2; ++rt)
    #pragma unroll
    for (int t = 0; t < 4; ++t)
      #pragma unroll
      for (int r = 0; r < 4; ++r)
        __builtin_nontemporal_store(
            f2k(acc[rt][t][r]),
            &keys[(size_t)(R + (rt << 4) + rbase + r) * NN + C + (t << 4) + cc]);
}

// ---- kernel 3: per-row select + sums. 1 row per 256-thread block ----
// 16 keys/lane in registers (no spill, no big LDS), NT key loads, block-wide
// bitwise binary search with 1 barrier/round. Rounds 6-9 proved the select
// math is cheap; the cost was the latency-bound key read at 2 blocks/CU and
// cross-XCD dirty-L2 service of freshly-written keys (NT fixes both sides).
__global__ __launch_bounds__(256) void nca_select(
    const float* __restrict__ x, const unsigned* __restrict__ keys,
    const int* __restrict__ tgt, float* __restrict__ row_loss,
    float* __restrict__ out) {
  __shared__ double   redD[4];
  __shared__ int      redI[2][4];
  __shared__ double   redP[4], redN[4];
  __shared__ float    redM[4];
  __shared__ int      redH[4], redC[4], redC2[4];
  __shared__ unsigned cbuf[64];
  __shared__ int      ccount;

  const int tid  = threadIdx.x;
  const int w    = tid >> 6;
  const int lane = tid & 63;
  const int i    = blockIdx.x;
  const int ti   = tgt[i];
  const unsigned* krow = keys + (size_t)i * NN;

  // f64 self-dot (decision sim[i][i] < 1.0), computed redundantly per wave
  double sx0 = (double)x[i * DD + lane], sx1 = (double)x[i * DD + lane + 64];
  const double selfd = wsum_d(sx0 * sx0 + sx1 * sx1);
  const bool self_pos = (selfd < 1.0);

  // stage 16 keys/lane into REGISTERS (NT loads); base = f64 row sum
  unsigned kv[16];
  double bs = 0.0;
  #pragma unroll
  for (int kk = 0; kk < 4; ++kk) {
    uint4v k4 = __builtin_nontemporal_load(
        reinterpret_cast<const uint4v*>(krow + (kk << 10) + (tid << 2)));
    #pragma unroll
    for (int q = 0; q < 4; ++q) {
      kv[kk * 4 + q] = k4[q];
      bs += (double)k2f(k4[q]);
    }
  }
  bs = wsum_d(bs);
  if (lane == 0) redD[w] = bs;
  __syncthreads();
  const float basef =
      (float)((redD[0] + redD[1] + redD[2] + redD[3]) * (1.0 / NN));

  // exclude self (sim>=1): max key (decodes to NaN in pass 2)
  if (!self_pos) {
    #pragma unroll
    for (int kk = 0; kk < 4; ++kk)
      #pragma unroll
      for (int q = 0; q < 4; ++q)
        if (((kk << 10) + (tid << 2) + q) == i) kv[kk * 4 + q] = 0xFFFFFFFFu;
  }

  // ---- exact rank-KSEL: block-wide bitwise binary search ----
  unsigned lo = 0;
  int nLo = 0, nHi = NN, b = 31, par = 0;
  while (b >= 0 && (nHi - nLo) > 64) {
    unsigned mid = lo | (1u << b);
    int c = 0;
    #pragma unroll
    for (int t = 0; t < 16; ++t) c += (kv[t] < mid) ? 1 : 0;
    c = wsum_i(c);
    if (lane == 0) redI[par][w] = c;
    __syncthreads();
    c = redI[par][0] + redI[par][1] + redI[par][2] + redI[par][3];
    par ^= 1;            // parity double-buffer: no 2nd barrier needed
    if (c <= KSEL) { lo = mid; nLo = c; }
    else nHi = c;
    --b;
  }

  unsigned keysel;
  if ((nHi - nLo) <= 64) {
    // compact the <=64 window candidates into cbuf, then register ballot
    const int shift = b + 1;                 // 0..31 (loop ran >= once)
    const unsigned pfx = lo >> shift;
    if (tid == 0) ccount = 0;
    __syncthreads();
    #pragma unroll
    for (int t = 0; t < 16; ++t)
      if ((kv[t] >> shift) == pfx) {
        int p = atomicAdd(&ccount, 1);
        cbuf[p] = kv[t];
      }
    __syncthreads();
    const int total = ccount;                // == nHi - nLo <= 64
    unsigned v = cbuf[lane];                 // garbage if lane >= total (masked)
    unsigned long long amask =
        (total >= 64) ? ~0ull : ((1ull << total) - 1ull);
    int ww = KSEL - nLo;                     // 0-based rank within window
    for (int bb = b; bb >= 0; --bb) {
      unsigned long long z = __ballot(((amask >> lane) & 1ull) &&
                                      (((v >> bb) & 1u) == 0u));
      int zc = __popcll(z);
      if (ww < zc) amask = z;
      else { ww -= zc; amask &= ~z; }
    }
    int first = __ffsll((unsigned long long)amask) - 1;
    keysel = __shfl(v, first, 64);           // same result in every wave
  } else {
    keysel = lo;  // bits exhausted with >64 exact ties: key fully resolved
  }
  const float thr = k2f(keysel);

  // ---- pass 2: weighted sums below threshold, min positive, has-pos ----
  double psum = 0.0, nsum = 0.0;
  float minp = __builtin_inff();
  int hasp = 0;
  #pragma unroll
  for (int kk = 0; kk < 4; ++kk) {
    int4 t4 = *reinterpret_cast<const int4*>(tgt + (kk << 10) + (tid << 2));
    int tj[4] = {t4.x, t4.y, t4.z, t4.w};
    #pragma unroll
    for (int q = 0; q < 4; ++q) {
      int j = (kk << 10) + (tid << 2) + q;
      float s = k2f(kv[kk * 4 + q]);  // NaN for excluded self -> predicates false
      bool same = (tj[q] == ti);
      bool vpos = same && ((j == i) ? self_pos : (s < 1.0f));
      if (vpos) minp = fminf(minp, s);
      if (s < thr) {
        float wgt = expf(ALPHA_C * (basef - s));
        if (vpos) { psum += (double)wgt; hasp = 1; }
        else if (!same) nsum += (double)wgt;
      }
    }
  }
  psum = wsum_d(psum); nsum = wsum_d(nsum);
  minp = wmin_f(minp); hasp = wsum_i(hasp);
  if (lane == 0) { redP[w] = psum; redN[w] = nsum; redM[w] = minp; redH[w] = hasp; }
  __syncthreads();
  const double tpsum = redP[0] + redP[1] + redP[2] + redP[3];
  const double tnsum = redN[0] + redN[1] + redN[2] + redN[3];
  const float  tminp = fminf(fminf(redM[0], redM[1]), fminf(redM[2], redM[3]));
  const int    thasp = redH[0] + redH[1] + redH[2] + redH[3];

  // diagnostics from the last row only (block-uniform branch)
  if (i == NN - 1) {
    __syncthreads();   // protect reuse of redP/redN
    double pss = 0.0, nss = 0.0;
    int pct = 0, nct = 0;
    #pragma unroll
    for (int kk = 0; kk < 4; ++kk) {
      int4 t4 = *reinterpret_cast<const int4*>(tgt + (kk << 10) + (tid << 2));
      int tj[4] = {t4.x, t4.y, t4.z, t4.w};
      #pragma unroll
      for (int q = 0; q < 4; ++q) {
        int j = (kk << 10) + (tid << 2) + q;
        float s = k2f(kv[kk * 4 + q]);
        bool same = (tj[q] == ti);
        bool vpos = same && ((j == i) ? self_pos : (s < 1.0f));
        if (vpos) { pss += (double)s; pct++; }
        if (!same) { nss += (double)s; nct++; }
      }
    }
    pss = wsum_d(pss); nss = wsum_d(nss);
    pct = wsum_i(pct); nct = wsum_i(nct);
    if (lane == 0) { redP[w] = pss; redN[w] = nss; redC[w] = pct; redC2[w] = nct; }
    __syncthreads();
    if (tid == 0) {
      out[2] = (float)((redP[0] + redP[1] + redP[2] + redP[3]) /
                       (double)(redC[0] + redC[1] + redC[2] + redC[3]));
      out[3] = (float)((redN[0] + redN[1] + redN[2] + redN[3]) /
                       (double)(redC2[0] + redC2[1] + redC2[2] + redC2[3]));
    }
  }

  if (tid == 0) {
    float pl = (thasp > 0) ? (float)tpsum
                           : expf(ALPHA_C * (basef - tminp));
    row_loss[i] = -logf(pl / (pl + (float)tnsum));
  }
}

// ---- kernel 4: deterministic mean of per-row losses ----
__global__ void nca_final(const float* __restrict__ row_loss, float* __restrict__ out) {
  __shared__ double redd[4];
  int tid = threadIdx.x;
  double s = 0.0;
  for (int i = tid; i < NN; i += 256) s += (double)row_loss[i];
  #pragma unroll
  for (int m = 32; m; m >>= 1) s += __shfl_xor(s, m, 64);
  if ((tid & 63) == 0) redd[tid >> 6] = s;
  __syncthreads();
  if (tid == 0) {
    double tot = redd[0] + redd[1] + redd[2] + redd[3];
    out[0] = (float)(tot * (1.0 / NN));
    out[1] = 0.0f;
  }
}

extern "C" void kernel_launch(void* const* d_in, const int* in_sizes, int n_in,
                              void* d_out, int out_size, void* d_ws, size_t ws_size,
                              hipStream_t stream) {
  const float* x  = (const float*)d_in[0];
  const int* tgt  = (const int*)d_in[1];
  float* out      = (float*)d_out;

  // ws layout: xhi (1 MB) | xlo (1 MB) | row_loss (16 KB) | keys (64 MB)
  short* xhi       = (short*)d_ws;
  short* xlo       = xhi + (size_t)NN * DD;
  float* row_loss  = (float*)(xlo + (size_t)NN * DD);
  unsigned* keys   = (unsigned*)(row_loss + NN);

  nca_prep<<<(NN * DD / 4) / 256, 256, 0, stream>>>(x, xhi, xlo);
  nca_gemm<<<(NN / 32) * (NN / 256), 256, 0, stream>>>(xhi, xlo, keys);
  nca_select<<<NN, 256, 0, stream>>>(x, keys, tgt, row_loss, out);
  nca_final<<<1, 256, 0, stream>>>(row_loss, out);
}

// Round 11
// 106.286 us; speedup vs baseline: 1.1517x; 1.0338x over previous
//
#include <hip/hip_runtime.h>
#include <math.h>

#define NN 4096
#define DD 128
#define ALPHA_C 16.0f
#define KSEL 32         // threshold = (K+1)-th smallest, 0-based index K

typedef __attribute__((ext_vector_type(8))) short bf16x8;
typedef __attribute__((ext_vector_type(4))) float f32x4;
typedef __attribute__((ext_vector_type(4))) unsigned uint4v;

// ---- float <-> order-preserving u32 key ----
__device__ __forceinline__ unsigned f2k(float f) {
  unsigned b = __float_as_uint(f);
  return (b & 0x80000000u) ? ~b : (b | 0x80000000u);
}
__device__ __forceinline__ float k2f(unsigned k) {
  unsigned b = (k & 0x80000000u) ? (k & 0x7FFFFFFFu) : ~k;
  return __uint_as_float(b);
}

// ---- wave (64-lane) butterfly reductions ----
__device__ __forceinline__ double wsum_d(double v) {
  #pragma unroll
  for (int m = 32; m; m >>= 1) v += __shfl_xor(v, m, 64);
  return v;
}
__device__ __forceinline__ int wsum_i(int v) {
  #pragma unroll
  for (int m = 32; m; m >>= 1) v += __shfl_xor(v, m, 64);
  return v;
}
__device__ __forceinline__ float wmin_f(float v) {
  #pragma unroll
  for (int m = 32; m; m >>= 1) v = fminf(v, __shfl_xor(v, m, 64));
  return v;
}

// ---- kernel 1: split x (f32) -> bf16 hi + bf16 lo (RNE both) ----
__global__ __launch_bounds__(256) void nca_prep(
    const float* __restrict__ x, short* __restrict__ xhi, short* __restrict__ xlo) {
  int idx = blockIdx.x * blockDim.x + threadIdx.x;   // 0 .. N*D/4-1
  float4 v = reinterpret_cast<const float4*>(x)[idx];
  float vv[4] = {v.x, v.y, v.z, v.w};
  short h[4], l[4];
  #pragma unroll
  for (int q = 0; q < 4; ++q) {
    unsigned u  = __float_as_uint(vv[q]);
    unsigned hb = (u + 0x7FFFu + ((u >> 16) & 1u)) >> 16;
    float hf    = __uint_as_float(hb << 16);
    float lf    = vv[q] - hf;
    unsigned ul = __float_as_uint(lf);
    unsigned lb = (ul + 0x7FFFu + ((ul >> 16) & 1u)) >> 16;
    h[q] = (short)hb; l[q] = (short)lb;
  }
  reinterpret_cast<short4*>(xhi)[idx] = make_short4(h[0], h[1], h[2], h[3]);
  reinterpret_cast<short4*>(xlo)[idx] = make_short4(l[0], l[1], l[2], l[3]);
}

// ---- kernel 2: MFMA GEMM sim = X X^T (bf16x3) -> u32 keys ----
// block: 32 rows x 256 cols, 4 waves; wave: 32 rows x 64 cols = 2x4 16x16 tiles
__global__ __launch_bounds__(256) void nca_gemm(
    const short* __restrict__ xhi, const short* __restrict__ xlo,
    unsigned* __restrict__ keys) {
  const int tid = threadIdx.x;
  const int w   = tid >> 6;
  const int l   = tid & 63;
  const int rg  = blockIdx.x >> 4;
  const int cg  = blockIdx.x & 15;
  const int R   = rg << 5;                 // 32 rows
  const int C   = (cg << 8) + (w << 6);    // 64 cols per wave
  const int lr  = l & 15;                  // row/col within tile
  const int lk  = (l >> 4) << 3;           // k-offset within 32-wide k-block

  f32x4 acc[2][4];
  #pragma unroll
  for (int rt = 0; rt < 2; ++rt)
    #pragma unroll
    for (int t = 0; t < 4; ++t) acc[rt][t] = (f32x4){0.f, 0.f, 0.f, 0.f};

  #pragma unroll
  for (int kb = 0; kb < 4; ++kb) {
    const int ko = (kb << 5) + lk;
    bf16x8 ah[2], al[2], bh[4], bl[4];
    #pragma unroll
    for (int rt = 0; rt < 2; ++rt) {
      const size_t off = (size_t)(R + (rt << 4) + lr) * DD + ko;
      ah[rt] = *reinterpret_cast<const bf16x8*>(xhi + off);
      al[rt] = *reinterpret_cast<const bf16x8*>(xlo + off);
    }
    #pragma unroll
    for (int t = 0; t < 4; ++t) {
      const size_t off = (size_t)(C + (t << 4) + lr) * DD + ko;
      bh[t] = *reinterpret_cast<const bf16x8*>(xhi + off);
      bl[t] = *reinterpret_cast<const bf16x8*>(xlo + off);
    }
    #pragma unroll
    for (int rt = 0; rt < 2; ++rt)
      #pragma unroll
      for (int t = 0; t < 4; ++t) {
        acc[rt][t] = __builtin_amdgcn_mfma_f32_16x16x32_bf16(ah[rt], bh[t], acc[rt][t], 0, 0, 0);
        acc[rt][t] = __builtin_amdgcn_mfma_f32_16x16x32_bf16(ah[rt], bl[t], acc[rt][t], 0, 0, 0);
        acc[rt][t] = __builtin_amdgcn_mfma_f32_16x16x32_bf16(al[rt], bh[t], acc[rt][t], 0, 0, 0);
      }
  }

  // C/D layout (m89-verified): col = lane&15, row = (lane>>4)*4 + reg
  const int rbase = (l >> 4) << 2;
  const int cc    = l & 15;
  #pragma unroll
  for (int rt = 0; rt < 2; ++rt)
    #pragma unroll
    for (int t = 0; t < 4; ++t)
      #pragma unroll
      for (int r = 0; r < 4; ++r)
        keys[(size_t)(R + (rt << 4) + rbase + r) * NN + C + (t << 4) + cc] =
            f2k(acc[rt][t][r]);
}

// ---- kernel 3: per-row select + sums. 1 row per 256-thread block ----
// Exact rank-KSEL with a guarded two-pivot fast path: for N(0,1/128)-like
// sims, keys in [f2k(-0.245), f2k(-0.19)) bracket rank 32 with <=64
// candidates (one barriered count round instead of ~18). Any row violating
// the guard falls back to the exact bitwise binary search (round-10 proven).
__global__ __launch_bounds__(256) void nca_select(
    const float* __restrict__ x, const unsigned* __restrict__ keys,
    const int* __restrict__ tgt, float* __restrict__ row_loss,
    float* __restrict__ out) {
  __shared__ double   redD[4];
  __shared__ int      redI[2][4];
  __shared__ double   redP[4], redN[4];
  __shared__ float    redM[4];
  __shared__ int      redH[4], redC[4], redC2[4];
  __shared__ unsigned cbuf[64];
  __shared__ int      ccount;

  const int tid  = threadIdx.x;
  const int w    = tid >> 6;
  const int lane = tid & 63;
  const int i    = blockIdx.x;
  const int ti   = tgt[i];
  const unsigned* krow = keys + (size_t)i * NN;

  // f64 self-dot (decision sim[i][i] < 1.0), computed redundantly per wave
  double sx0 = (double)x[i * DD + lane], sx1 = (double)x[i * DD + lane + 64];
  const double selfd = wsum_d(sx0 * sx0 + sx1 * sx1);
  const bool self_pos = (selfd < 1.0);

  // stage 16 keys/lane into REGISTERS; base = f64 row sum
  unsigned kv[16];
  double bs = 0.0;
  #pragma unroll
  for (int kk = 0; kk < 4; ++kk) {
    uint4v k4 = *reinterpret_cast<const uint4v*>(krow + (kk << 10) + (tid << 2));
    #pragma unroll
    for (int q = 0; q < 4; ++q) {
      kv[kk * 4 + q] = k4[q];
      bs += (double)k2f(k4[q]);
    }
  }
  bs = wsum_d(bs);
  if (lane == 0) redD[w] = bs;
  __syncthreads();
  const float basef =
      (float)((redD[0] + redD[1] + redD[2] + redD[3]) * (1.0 / NN));

  // exclude self (sim>=1): max key (decodes to NaN in pass 2)
  if (!self_pos) {
    #pragma unroll
    for (int kk = 0; kk < 4; ++kk)
      #pragma unroll
      for (int q = 0; q < 4; ++q)
        if (((kk << 10) + (tid << 2) + q) == i) kv[kk * 4 + q] = 0xFFFFFFFFu;
  }

  // ---- fast path: one count round against two fixed pivots ----
  const unsigned P1 = f2k(-0.245f), P2 = f2k(-0.19f);
  {
    int c1 = 0, c2 = 0;
    #pragma unroll
    for (int t = 0; t < 16; ++t) {
      c1 += (kv[t] < P1) ? 1 : 0;
      c2 += (kv[t] < P2) ? 1 : 0;
    }
    c1 = wsum_i(c1); c2 = wsum_i(c2);
    if (lane == 0) { redI[0][w] = c1; redI[1][w] = c2; }
  }
  __syncthreads();
  const int C1 = redI[0][0] + redI[0][1] + redI[0][2] + redI[0][3];
  const int C2 = redI[1][0] + redI[1][1] + redI[1][2] + redI[1][3];
  const bool fast = (C1 <= KSEL) && (C2 > KSEL) && (C2 - C1 <= 64);
  __syncthreads();   // redI reads done before fallback loop may rewrite

  bool resolved = false;
  unsigned keysel = 0;
  unsigned candmask = 0;   // bit t: kv[t] is a window candidate
  int base = 0;            // count(keys < window-lo)

  if (fast) {
    #pragma unroll
    for (int t = 0; t < 16; ++t)
      if (kv[t] >= P1 && kv[t] < P2) candmask |= (1u << t);
    base = C1;
  } else {
    // ---- exact bitwise binary search (round-10 proven) ----
    unsigned lo = 0;
    int nLo = 0, nHi = NN, b = 31, par = 0;
    while (b >= 0 && (nHi - nLo) > 64) {
      unsigned mid = lo | (1u << b);
      int c = 0;
      #pragma unroll
      for (int t = 0; t < 16; ++t) c += (kv[t] < mid) ? 1 : 0;
      c = wsum_i(c);
      if (lane == 0) redI[par][w] = c;
      __syncthreads();
      c = redI[par][0] + redI[par][1] + redI[par][2] + redI[par][3];
      par ^= 1;            // parity double-buffer: no 2nd barrier needed
      if (c <= KSEL) { lo = mid; nLo = c; }
      else nHi = c;
      --b;
    }
    if ((nHi - nLo) <= 64) {
      const int shift = b + 1;               // 0..31 (loop ran >= once)
      const unsigned pfx = lo >> shift;
      #pragma unroll
      for (int t = 0; t < 16; ++t)
        if ((kv[t] >> shift) == pfx) candmask |= (1u << t);
      base = nLo;
    } else {
      keysel = lo;  // bits exhausted with >64 exact ties: key fully resolved
      resolved = true;
    }
  }

  if (!resolved) {
    // compact window candidates into cbuf, then register ballot finish
    if (tid == 0) ccount = 0;
    __syncthreads();
    #pragma unroll
    for (int t = 0; t < 16; ++t)
      if (candmask & (1u << t)) {
        int p = atomicAdd(&ccount, 1);
        cbuf[p] = kv[t];
      }
    __syncthreads();
    const int total = ccount;                // <= 64 by construction
    unsigned v = cbuf[lane];                 // garbage if lane >= total (masked)
    unsigned long long amask =
        (total >= 64) ? ~0ull : ((1ull << total) - 1ull);
    int ww = KSEL - base;                    // 0-based rank within window
    for (int bb = 31; bb >= 0; --bb) {       // all-equal bits are no-ops
      unsigned long long z = __ballot(((amask >> lane) & 1ull) &&
                                      (((v >> bb) & 1u) == 0u));
      int zc = __popcll(z);
      if (ww < zc) amask = z;
      else { ww -= zc; amask &= ~z; }
    }
    int first = __ffsll((unsigned long long)amask) - 1;
    keysel = __shfl(v, first, 64);           // same result in every wave
  }
  const float thr = k2f(keysel);

  // ---- pass 2: weighted sums below threshold, min positive, has-pos ----
  double psum = 0.0, nsum = 0.0;
  float minp = __builtin_inff();
  int hasp = 0;
  #pragma unroll
  for (int kk = 0; kk < 4; ++kk) {
    int4 t4 = *reinterpret_cast<const int4*>(tgt + (kk << 10) + (tid << 2));
    int tj[4] = {t4.x, t4.y, t4.z, t4.w};
    #pragma unroll
    for (int q = 0; q < 4; ++q) {
      int j = (kk << 10) + (tid << 2) + q;
      float s = k2f(kv[kk * 4 + q]);  // NaN for excluded self -> predicates false
      bool same = (tj[q] == ti);
      bool vpos = same && ((j == i) ? self_pos : (s < 1.0f));
      if (vpos) minp = fminf(minp, s);
      if (s < thr) {
        float wgt = expf(ALPHA_C * (basef - s));
        if (vpos) { psum += (double)wgt; hasp = 1; }
        else if (!same) nsum += (double)wgt;
      }
    }
  }
  psum = wsum_d(psum); nsum = wsum_d(nsum);
  minp = wmin_f(minp); hasp = wsum_i(hasp);
  if (lane == 0) { redP[w] = psum; redN[w] = nsum; redM[w] = minp; redH[w] = hasp; }
  __syncthreads();
  const double tpsum = redP[0] + redP[1] + redP[2] + redP[3];
  const double tnsum = redN[0] + redN[1] + redN[2] + redN[3];
  const float  tminp = fminf(fminf(redM[0], redM[1]), fminf(redM[2], redM[3]));
  const int    thasp = redH[0] + redH[1] + redH[2] + redH[3];

  // diagnostics from the last row only (block-uniform branch)
  if (i == NN - 1) {
    __syncthreads();   // protect reuse of redP/redN
    double pss = 0.0, nss = 0.0;
    int pct = 0, nct = 0;
    #pragma unroll
    for (int kk = 0; kk < 4; ++kk) {
      int4 t4 = *reinterpret_cast<const int4*>(tgt + (kk << 10) + (tid << 2));
      int tj[4] = {t4.x, t4.y, t4.z, t4.w};
      #pragma unroll
      for (int q = 0; q < 4; ++q) {
        int j = (kk << 10) + (tid << 2) + q;
        float s = k2f(kv[kk * 4 + q]);
        bool same = (tj[q] == ti);
        bool vpos = same && ((j == i) ? self_pos : (s < 1.0f));
        if (vpos) { pss += (double)s; pct++; }
        if (!same) { nss += (double)s; nct++; }
      }
    }
    pss = wsum_d(pss); nss = wsum_d(nss);
    pct = wsum_i(pct); nct = wsum_i(nct);
    if (lane == 0) { redP[w] = pss; redN[w] = nss; redC[w] = pct; redC2[w] = nct; }
    __syncthreads();
    if (tid == 0) {
      out[2] = (float)((redP[0] + redP[1] + redP[2] + redP[3]) /
                       (double)(redC[0] + redC[1] + redC[2] + redC[3]));
      out[3] = (float)((redN[0] + redN[1] + redN[2] + redN[3]) /
                       (double)(redC2[0] + redC2[1] + redC2[2] + redC2[3]));
    }
  }

  if (tid == 0) {
    float pl = (thasp > 0) ? (float)tpsum
                           : expf(ALPHA_C * (basef - tminp));
    row_loss[i] = -logf(pl / (pl + (float)tnsum));
  }
}

// ---- kernel 4: deterministic mean of per-row losses ----
__global__ void nca_final(const float* __restrict__ row_loss, float* __restrict__ out) {
  __shared__ double redd[4];
  int tid = threadIdx.x;
  double s = 0.0;
  for (int i = tid; i < NN; i += 256) s += (double)row_loss[i];
  #pragma unroll
  for (int m = 32; m; m >>= 1) s += __shfl_xor(s, m, 64);
  if ((tid & 63) == 0) redd[tid >> 6] = s;
  __syncthreads();
  if (tid == 0) {
    double tot = redd[0] + redd[1] + redd[2] + redd[3];
    out[0] = (float)(tot * (1.0 / NN));
    out[1] = 0.0f;
  }
}

extern "C" void kernel_launch(void* const* d_in, const int* in_sizes, int n_in,
                              void* d_out, int out_size, void* d_ws, size_t ws_size,
                              hipStream_t stream) {
  const float* x  = (const float*)d_in[0];
  const int* tgt  = (const int*)d_in[1];
  float* out      = (float*)d_out;

  // ws layout: xhi (1 MB) | xlo (1 MB) | row_loss (16 KB) | keys (64 MB)
  short* xhi       = (short*)d_ws;
  short* xlo       = xhi + (size_t)NN * DD;
  float* row_loss  = (float*)(xlo + (size_t)NN * DD);
  unsigned* keys   = (unsigned*)(row_loss + NN);

  nca_prep<<<(NN * DD / 4) / 256, 256, 0, stream>>>(x, xhi, xlo);
  nca_gemm<<<(NN / 32) * (NN / 256), 256, 0, stream>>>(xhi, xlo, keys);
  nca_select<<<NN, 256, 0, stream>>>(x, keys, tgt, row_loss, out);
  nca_final<<<1, 256, 0, stream>>>(row_loss, out);
}

// Round 12
// 80.370 us; speedup vs baseline: 1.5230x; 1.3225x over previous
//
#include <hip/hip_runtime.h>
#include <math.h>

#define NN 4096
#define DD 128
#define ALPHA_C 16.0f
#define KSEL 32         // threshold = (K+1)-th smallest, 0-based index K

typedef __attribute__((ext_vector_type(8))) short bf16x8;
typedef __attribute__((ext_vector_type(4))) float f32x4;
typedef __attribute__((ext_vector_type(4))) unsigned uint4v;

// ---- float <-> order-preserving u32 key ----
__device__ __forceinline__ unsigned f2k(float f) {
  unsigned b = __float_as_uint(f);
  return (b & 0x80000000u) ? ~b : (b | 0x80000000u);
}
__device__ __forceinline__ float k2f(unsigned k) {
  unsigned b = (k & 0x80000000u) ? (k & 0x7FFFFFFFu) : ~k;
  return __uint_as_float(b);
}

// ---- wave (64-lane) butterfly reductions ----
__device__ __forceinline__ double wsum_d(double v) {
  #pragma unroll
  for (int m = 32; m; m >>= 1) v += __shfl_xor(v, m, 64);
  return v;
}
__device__ __forceinline__ int wsum_i(int v) {
  #pragma unroll
  for (int m = 32; m; m >>= 1) v += __shfl_xor(v, m, 64);
  return v;
}
__device__ __forceinline__ float wmin_f(float v) {
  #pragma unroll
  for (int m = 32; m; m >>= 1) v = fminf(v, __shfl_xor(v, m, 64));
  return v;
}

// ---- kernel 1: split x -> bf16 hi/lo in FRAGMENT-MAJOR layout ----
// Fragment f = (rg, kb, lane): rows rg*16+(lane&15), k = kb*32+(lane>>4)*8..+8.
// Stored at xpk + f*8 shorts: gemm operand loads become lane-contiguous
// (1 KB fully-coalesced per instruction) instead of 64 scattered lines.
__global__ __launch_bounds__(256) void nca_prep(
    const float* __restrict__ x, short* __restrict__ xhi, short* __restrict__ xlo) {
  const int f  = blockIdx.x * blockDim.x + threadIdx.x;  // 0 .. N*D/8-1
  const int l  = f & 63;
  const int kb = (f >> 6) & 3;
  const int rg = f >> 8;
  const int row = (rg << 4) + (l & 15);
  const int k0  = (kb << 5) + ((l >> 4) << 3);
  const float* src = x + (size_t)row * DD + k0;
  float4 v0 = *reinterpret_cast<const float4*>(src);
  float4 v1 = *reinterpret_cast<const float4*>(src + 4);
  float vv[8] = {v0.x, v0.y, v0.z, v0.w, v1.x, v1.y, v1.z, v1.w};
  bf16x8 h, lo;
  #pragma unroll
  for (int q = 0; q < 8; ++q) {
    unsigned u  = __float_as_uint(vv[q]);
    unsigned hb = (u + 0x7FFFu + ((u >> 16) & 1u)) >> 16;
    float hf    = __uint_as_float(hb << 16);
    float lf    = vv[q] - hf;
    unsigned ul = __float_as_uint(lf);
    unsigned lb = (ul + 0x7FFFu + ((ul >> 16) & 1u)) >> 16;
    h[q] = (short)hb; lo[q] = (short)lb;
  }
  *reinterpret_cast<bf16x8*>(xhi + (size_t)f * 8) = h;
  *reinterpret_cast<bf16x8*>(xlo + (size_t)f * 8) = lo;
}

// ---- kernel 2: MFMA GEMM sim = X X^T (bf16x3) -> u32 keys ----
// block: 32 rows x 256 cols, 4 waves; wave: 32 rows x 64 cols = 2x4 16x16 tiles
// All operand loads are single coalesced 16B/lane reads from the packed layout.
__global__ __launch_bounds__(256) void nca_gemm(
    const short* __restrict__ xhi, const short* __restrict__ xlo,
    unsigned* __restrict__ keys) {
  const int tid = threadIdx.x;
  const int w   = tid >> 6;
  const int l   = tid & 63;
  const int rg  = blockIdx.x >> 4;
  const int cg  = blockIdx.x & 15;
  const int R   = rg << 5;                 // 32 rows
  const int C   = (cg << 8) + (w << 6);    // 64 cols per wave
  const int rga = rg << 1;                 // A row-group base (R>>4)
  const int rgb = (cg << 4) + (w << 2);    // B row-group base (C>>4)

  f32x4 acc[2][4];
  #pragma unroll
  for (int rt = 0; rt < 2; ++rt)
    #pragma unroll
    for (int t = 0; t < 4; ++t) acc[rt][t] = (f32x4){0.f, 0.f, 0.f, 0.f};

  #pragma unroll
  for (int kb = 0; kb < 4; ++kb) {
    bf16x8 ah[2], al[2], bh[4], bl[4];
    #pragma unroll
    for (int rt = 0; rt < 2; ++rt) {
      const size_t off = ((size_t)((rga + rt) * 4 + kb) * 64 + l) * 8;
      ah[rt] = *reinterpret_cast<const bf16x8*>(xhi + off);
      al[rt] = *reinterpret_cast<const bf16x8*>(xlo + off);
    }
    #pragma unroll
    for (int t = 0; t < 4; ++t) {
      const size_t off = ((size_t)((rgb + t) * 4 + kb) * 64 + l) * 8;
      bh[t] = *reinterpret_cast<const bf16x8*>(xhi + off);
      bl[t] = *reinterpret_cast<const bf16x8*>(xlo + off);
    }
    #pragma unroll
    for (int rt = 0; rt < 2; ++rt)
      #pragma unroll
      for (int t = 0; t < 4; ++t) {
        acc[rt][t] = __builtin_amdgcn_mfma_f32_16x16x32_bf16(ah[rt], bh[t], acc[rt][t], 0, 0, 0);
        acc[rt][t] = __builtin_amdgcn_mfma_f32_16x16x32_bf16(ah[rt], bl[t], acc[rt][t], 0, 0, 0);
        acc[rt][t] = __builtin_amdgcn_mfma_f32_16x16x32_bf16(al[rt], bh[t], acc[rt][t], 0, 0, 0);
      }
  }

  // C/D layout (m89-verified): col = lane&15, row = (lane>>4)*4 + reg
  const int rbase = (l >> 4) << 2;
  const int cc    = l & 15;
  #pragma unroll
  for (int rt = 0; rt < 2; ++rt)
    #pragma unroll
    for (int t = 0; t < 4; ++t)
      #pragma unroll
      for (int r = 0; r < 4; ++r)
        keys[(size_t)(R + (rt << 4) + rbase + r) * NN + C + (t << 4) + cc] =
            f2k(acc[rt][t][r]);
}

// ---- kernel 3: per-row select + sums. 1 row per 256-thread block ----
// Exact rank-KSEL with a guarded two-pivot fast path; fallback = exact
// bitwise binary search (round-10 proven). Keys in registers, 16/lane.
__global__ __launch_bounds__(256) void nca_select(
    const float* __restrict__ x, const unsigned* __restrict__ keys,
    const int* __restrict__ tgt, float* __restrict__ row_loss,
    float* __restrict__ out) {
  __shared__ double   redD[4];
  __shared__ int      redI[2][4];
  __shared__ double   redP[4], redN[4];
  __shared__ float    redM[4];
  __shared__ int      redH[4], redC[4], redC2[4];
  __shared__ unsigned cbuf[64];
  __shared__ int      ccount;

  const int tid  = threadIdx.x;
  const int w    = tid >> 6;
  const int lane = tid & 63;
  const int i    = blockIdx.x;
  const int ti   = tgt[i];
  const unsigned* krow = keys + (size_t)i * NN;

  // f64 self-dot (decision sim[i][i] < 1.0), computed redundantly per wave
  double sx0 = (double)x[i * DD + lane], sx1 = (double)x[i * DD + lane + 64];
  const double selfd = wsum_d(sx0 * sx0 + sx1 * sx1);
  const bool self_pos = (selfd < 1.0);

  // stage 16 keys/lane into REGISTERS; base = f64 row sum
  unsigned kv[16];
  double bs = 0.0;
  #pragma unroll
  for (int kk = 0; kk < 4; ++kk) {
    uint4v k4 = *reinterpret_cast<const uint4v*>(krow + (kk << 10) + (tid << 2));
    #pragma unroll
    for (int q = 0; q < 4; ++q) {
      kv[kk * 4 + q] = k4[q];
      bs += (double)k2f(k4[q]);
    }
  }
  bs = wsum_d(bs);
  if (lane == 0) redD[w] = bs;
  __syncthreads();
  const float basef =
      (float)((redD[0] + redD[1] + redD[2] + redD[3]) * (1.0 / NN));

  // exclude self (sim>=1): max key (decodes to NaN in pass 2)
  if (!self_pos) {
    #pragma unroll
    for (int kk = 0; kk < 4; ++kk)
      #pragma unroll
      for (int q = 0; q < 4; ++q)
        if (((kk << 10) + (tid << 2) + q) == i) kv[kk * 4 + q] = 0xFFFFFFFFu;
  }

  // ---- fast path: one count round against two fixed pivots ----
  const unsigned P1 = f2k(-0.245f), P2 = f2k(-0.19f);
  {
    int c1 = 0, c2 = 0;
    #pragma unroll
    for (int t = 0; t < 16; ++t) {
      c1 += (kv[t] < P1) ? 1 : 0;
      c2 += (kv[t] < P2) ? 1 : 0;
    }
    c1 = wsum_i(c1); c2 = wsum_i(c2);
    if (lane == 0) { redI[0][w] = c1; redI[1][w] = c2; }
  }
  __syncthreads();
  const int C1 = redI[0][0] + redI[0][1] + redI[0][2] + redI[0][3];
  const int C2 = redI[1][0] + redI[1][1] + redI[1][2] + redI[1][3];
  const bool fast = (C1 <= KSEL) && (C2 > KSEL) && (C2 - C1 <= 64);
  __syncthreads();   // redI reads done before fallback loop may rewrite

  bool resolved = false;
  unsigned keysel = 0;
  unsigned candmask = 0;   // bit t: kv[t] is a window candidate
  int base = 0;            // count(keys < window-lo)

  if (fast) {
    #pragma unroll
    for (int t = 0; t < 16; ++t)
      if (kv[t] >= P1 && kv[t] < P2) candmask |= (1u << t);
    base = C1;
  } else {
    // ---- exact bitwise binary search (round-10 proven) ----
    unsigned lo = 0;
    int nLo = 0, nHi = NN, b = 31, par = 0;
    while (b >= 0 && (nHi - nLo) > 64) {
      unsigned mid = lo | (1u << b);
      int c = 0;
      #pragma unroll
      for (int t = 0; t < 16; ++t) c += (kv[t] < mid) ? 1 : 0;
      c = wsum_i(c);
      if (lane == 0) redI[par][w] = c;
      __syncthreads();
      c = redI[par][0] + redI[par][1] + redI[par][2] + redI[par][3];
      par ^= 1;            // parity double-buffer: no 2nd barrier needed
      if (c <= KSEL) { lo = mid; nLo = c; }
      else nHi = c;
      --b;
    }
    if ((nHi - nLo) <= 64) {
      const int shift = b + 1;               // 0..31 (loop ran >= once)
      const unsigned pfx = lo >> shift;
      #pragma unroll
      for (int t = 0; t < 16; ++t)
        if ((kv[t] >> shift) == pfx) candmask |= (1u << t);
      base = nLo;
    } else {
      keysel = lo;  // bits exhausted with >64 exact ties: key fully resolved
      resolved = true;
    }
  }

  if (!resolved) {
    // compact window candidates into cbuf, then register ballot finish
    if (tid == 0) ccount = 0;
    __syncthreads();
    #pragma unroll
    for (int t = 0; t < 16; ++t)
      if (candmask & (1u << t)) {
        int p = atomicAdd(&ccount, 1);
        cbuf[p] = kv[t];
      }
    __syncthreads();
    const int total = ccount;                // <= 64 by construction
    unsigned v = cbuf[lane];                 // garbage if lane >= total (masked)
    unsigned long long amask =
        (total >= 64) ? ~0ull : ((1ull << total) - 1ull);
    int ww = KSEL - base;                    // 0-based rank within window
    for (int bb = 31; bb >= 0; --bb) {       // all-equal bits are no-ops
      unsigned long long z = __ballot(((amask >> lane) & 1ull) &&
                                      (((v >> bb) & 1u) == 0u));
      int zc = __popcll(z);
      if (ww < zc) amask = z;
      else { ww -= zc; amask &= ~z; }
    }
    int first = __ffsll((unsigned long long)amask) - 1;
    keysel = __shfl(v, first, 64);           // same result in every wave
  }
  const float thr = k2f(keysel);

  // ---- pass 2: weighted sums below threshold, min positive, has-pos ----
  double psum = 0.0, nsum = 0.0;
  float minp = __builtin_inff();
  int hasp = 0;
  #pragma unroll
  for (int kk = 0; kk < 4; ++kk) {
    int4 t4 = *reinterpret_cast<const int4*>(tgt + (kk << 10) + (tid << 2));
    int tj[4] = {t4.x, t4.y, t4.z, t4.w};
    #pragma unroll
    for (int q = 0; q < 4; ++q) {
      int j = (kk << 10) + (tid << 2) + q;
      float s = k2f(kv[kk * 4 + q]);  // NaN for excluded self -> predicates false
      bool same = (tj[q] == ti);
      bool vpos = same && ((j == i) ? self_pos : (s < 1.0f));
      if (vpos) minp = fminf(minp, s);
      if (s < thr) {
        float wgt = expf(ALPHA_C * (basef - s));
        if (vpos) { psum += (double)wgt; hasp = 1; }
        else if (!same) nsum += (double)wgt;
      }
    }
  }
  psum = wsum_d(psum); nsum = wsum_d(nsum);
  minp = wmin_f(minp); hasp = wsum_i(hasp);
  if (lane == 0) { redP[w] = psum; redN[w] = nsum; redM[w] = minp; redH[w] = hasp; }
  __syncthreads();
  const double tpsum = redP[0] + redP[1] + redP[2] + redP[3];
  const double tnsum = redN[0] + redN[1] + redN[2] + redN[3];
  const float  tminp = fminf(fminf(redM[0], redM[1]), fminf(redM[2], redM[3]));
  const int    thasp = redH[0] + redH[1] + redH[2] + redH[3];

  // diagnostics from the last row only (block-uniform branch)
  if (i == NN - 1) {
    __syncthreads();   // protect reuse of redP/redN
    double pss = 0.0, nss = 0.0;
    int pct = 0, nct = 0;
    #pragma unroll
    for (int kk = 0; kk < 4; ++kk) {
      int4 t4 = *reinterpret_cast<const int4*>(tgt + (kk << 10) + (tid << 2));
      int tj[4] = {t4.x, t4.y, t4.z, t4.w};
      #pragma unroll
      for (int q = 0; q < 4; ++q) {
        int j = (kk << 10) + (tid << 2) + q;
        float s = k2f(kv[kk * 4 + q]);
        bool same = (tj[q] == ti);
        bool vpos = same && ((j == i) ? self_pos : (s < 1.0f));
        if (vpos) { pss += (double)s; pct++; }
        if (!same) { nss += (double)s; nct++; }
      }
    }
    pss = wsum_d(pss); nss = wsum_d(nss);
    pct = wsum_i(pct); nct = wsum_i(nct);
    if (lane == 0) { redP[w] = pss; redN[w] = nss; redC[w] = pct; redC2[w] = nct; }
    __syncthreads();
    if (tid == 0) {
      out[2] = (float)((redP[0] + redP[1] + redP[2] + redP[3]) /
                       (double)(redC[0] + redC[1] + redC[2] + redC[3]));
      out[3] = (float)((redN[0] + redN[1] + redN[2] + redN[3]) /
                       (double)(redC2[0] + redC2[1] + redC2[2] + redC2[3]));
    }
  }

  if (tid == 0) {
    float pl = (thasp > 0) ? (float)tpsum
                           : expf(ALPHA_C * (basef - tminp));
    row_loss[i] = -logf(pl / (pl + (float)tnsum));
  }
}

// ---- kernel 4: deterministic mean of per-row losses ----
__global__ void nca_final(const float* __restrict__ row_loss, float* __restrict__ out) {
  __shared__ double redd[4];
  int tid = threadIdx.x;
  double s = 0.0;
  for (int i = tid; i < NN; i += 256) s += (double)row_loss[i];
  #pragma unroll
  for (int m = 32; m; m >>= 1) s += __shfl_xor(s, m, 64);
  if ((tid & 63) == 0) redd[tid >> 6] = s;
  __syncthreads();
  if (tid == 0) {
    double tot = redd[0] + redd[1] + redd[2] + redd[3];
    out[0] = (float)(tot * (1.0 / NN));
    out[1] = 0.0f;
  }
}

extern "C" void kernel_launch(void* const* d_in, const int* in_sizes, int n_in,
                              void* d_out, int out_size, void* d_ws, size_t ws_size,
                              hipStream_t stream) {
  const float* x  = (const float*)d_in[0];
  const int* tgt  = (const int*)d_in[1];
  float* out      = (float*)d_out;

  // ws layout: xhi (1 MB) | xlo (1 MB) | row_loss (16 KB) | keys (64 MB)
  short* xhi       = (short*)d_ws;
  short* xlo       = xhi + (size_t)NN * DD;
  float* row_loss  = (float*)(xlo + (size_t)NN * DD);
  unsigned* keys   = (unsigned*)(row_loss + NN);

  nca_prep<<<(NN * DD / 8) / 256, 256, 0, stream>>>(x, xhi, xlo);
  nca_gemm<<<(NN / 32) * (NN / 256), 256, 0, stream>>>(xhi, xlo, keys);
  nca_select<<<NN, 256, 0, stream>>>(x, keys, tgt, row_loss, out);
  nca_final<<<1, 256, 0, stream>>>(row_loss, out);
}